// Round 13
// baseline (300.102 us; speedup 1.0000x reference)
//
#include <hip/hip_runtime.h>
#include <hip/hip_bf16.h>

#define SFP 36                     // u32 stride for packed tables (144 B rows, 16B-aligned)
#define SAP 40                     // u16 stride for packed u tile (80 B rows, 8B-aligned)
#define SB 34                      // float2 stride for f32 data buffers
#define KIDX(i) ((i) + ((i) >> 5)) // +1-per-32 padded f32 k-row addressing
#define W32A 0.19634954084936207f  // 2*pi/32
#define W1KA 0.006135923151542565f // 2*pi/1024
#define SC1K 0.0009765625f         // 2^-10 (exact)

__device__ __forceinline__ unsigned short f2bf(float x) {
    union { __hip_bfloat16 h; unsigned short u; } cv;
    cv.h = __float2bfloat16(x);
    return cv.u;
}
__device__ __forceinline__ float bfb2f(unsigned short b) {
    union { unsigned int u; float f; } cv;
    cv.u = ((unsigned int)b) << 16;
    return cv.f;
}
__device__ __forceinline__ float rt_bf(float x) { return bfb2f(f2bf(x)); }
__device__ __forceinline__ unsigned int pk2(float re, float im) {
    return (unsigned int)f2bf(re) | ((unsigned int)f2bf(im) << 16);
}
// unpack u32 (bf16re | bf16im<<16) -> float2 ; 2 VALU ops
__device__ __forceinline__ float2 upk(unsigned int p) {
    union { unsigned int u; float f; } a, b;
    a.u = p << 16;
    b.u = p & 0xFFFF0000u;
    return make_float2(a.f, b.f);
}
__device__ __forceinline__ float2 cmul2(float2 a, float2 b) {
    return make_float2(a.x*b.x - a.y*b.y, a.x*b.y + a.y*b.x);
}
// a += x*y
__device__ __forceinline__ void cmac2(float2& a, float2 x, float2 y) {
    a.x = fmaf(x.x, y.x, fmaf(-x.y, y.y, a.x));
    a.y = fmaf(x.x, y.y, fmaf( x.y, y.x, a.y));
}
// a += x*conj(y)
__device__ __forceinline__ void cmacC(float2& a, float2 x, float2 y) {
    a.x = fmaf(x.x, y.x, fmaf( x.y, y.y, a.x));
    a.y = fmaf(x.y, y.x, fmaf(-x.x, y.y, a.y));
}

__global__ __launch_bounds__(256) void tkmon3(
    const float* __restrict__ U, const float* __restrict__ K,
    float* __restrict__ OUT)
{
    __shared__ unsigned int cFp[32*SFP];    // packed F ; Finv = conj(F) via fma signs
    __shared__ unsigned int cTwip[32*SFP];  // packed twinv ; tw = conj(twinv)*2^-10
    __shared__ unsigned int cKfp[32*SFP];   // packed kfT: cKfp[i][j] = k_hat[i+32j]
    __shared__ unsigned short aAp[32*SAP];  // packed bf16 u tile: aAp[j][c] = u[32j+c]
    __shared__ float2 b1[32*SB];            // f32 stage buffer 1 (also CT scratch)
    __shared__ float2 b2[32*SB];            // f32 stage buffer 2 (hosts sk during kfft)

    const int t  = threadIdx.x;
    const int h  = blockIdx.x;
    const int r  = t >> 3;          // owned row 0..31
    const int c0 = (t & 7) << 2;    // owned cols c0..c0+3

    float* sk = reinterpret_cast<float*>(b2);   // k row (padded), dead after kfft

    // ---- load k row + generate packed twiddle tables ----
    #pragma unroll
    for (int s = 0; s < 4; ++s) {
        int i = t + 256*s;
        sk[KIDX(i)] = K[(size_t)h*1024 + i];
    }
    #pragma unroll
    for (int ii = 0; ii < 4; ++ii) {
        int idx = 4*t + ii;
        int rr = idx >> 5, cc = idx & 31;
        int m32 = (rr * cc) & 31;
        float s32, c32; sincosf((float)m32 * W32A, &s32, &c32);
        cFp[rr*SFP + cc] = pk2(c32, -s32);
        int m1k = (rr * cc) & 1023;
        float s1k, c1k; sincosf((float)m1k * W1KA, &s1k, &c1k);
        cTwip[rr*SFP + cc] = pk2(c1k, s1k);
    }
    __syncthreads();

    // ---- in-block 1024-pt k-FFT (2-stage CT, f32): cKfp[i][j] = pack(k_hat[i+32j]) ----
    {
        float2* cT = b1;    // scratch
        const int i0 = t >> 3, q0 = (t & 7) << 2;
        float si, ci;
        sincosf(W32A * (float)i0, &si, &ci);
        const float2 stepi = make_float2(ci, -si);
        #pragma unroll
        for (int cc = q0; cc < q0 + 4; ++cc) {
            float2 wv = make_float2(1.f, 0.f), acc = make_float2(0.f, 0.f);
            for (int rr = 0; rr < 32; ++rr) {
                float kv = sk[KIDX(32*rr + cc)];
                acc.x = fmaf(kv, wv.x, acc.x);
                acc.y = fmaf(kv, wv.y, acc.y);
                wv = cmul2(wv, stepi);
            }
            float sp, cp;
            sincosf(W1KA * (float)(i0 * cc), &sp, &cp);
            cT[i0*SB + cc] = cmul2(acc, make_float2(cp, -sp));
        }
        __syncthreads();
        #pragma unroll
        for (int j = q0; j < q0 + 4; ++j) {
            float sj, cj;
            sincosf(W32A * (float)j, &sj, &cj);
            const float2 stepj = make_float2(cj, -sj);
            float2 wv = make_float2(1.f, 0.f), acc = make_float2(0.f, 0.f);
            for (int cc = 0; cc < 32; ++cc) {
                float2 tv = cT[i0*SB + cc];
                acc.x = fmaf(tv.x, wv.x, fmaf(-tv.y, wv.y, acc.x));
                acc.y = fmaf(tv.x, wv.y, fmaf( tv.y, wv.x, acc.y));
                wv = cmul2(wv, stepj);
            }
            cKfp[i0*SFP + j] = pk2(acc.x, acc.y);
        }
        __syncthreads();   // cKfp ready; b1, b2 (sk) now free
    }

    // ---- prologue: stage tile 0 (packed bf16) ----
    {
        float4 uv = *reinterpret_cast<const float4*>(U + (size_t)h * 1024 + 4*t);
        ushort4 av;
        av.x = f2bf(uv.x); av.y = f2bf(uv.y); av.z = f2bf(uv.z); av.w = f2bf(uv.w);
        *reinterpret_cast<ushort4*>(&aAp[r*SAP + c0]) = av;
    }
    __syncthreads();

    // ==== 16 batch tiles ====
    for (int it = 0; it < 16; ++it) {
        const size_t base = ((size_t)it * 1024 + h) * 1024;

        // S1: X1[i][c] = sum_j F[i][j]*A[j][c] ; * tw (= conj(twinv)*2^-10) ; -> b1
        {
            float2 a0={0,0}, a1={0,0}, a2={0,0}, a3={0,0};
            #pragma unroll 16
            for (int j = 0; j < 32; ++j) {
                float2 fv = upk(cFp[r*SFP + j]);
                ushort4 a4 = *reinterpret_cast<const ushort4*>(&aAp[j*SAP + c0]);
                float v0 = bfb2f(a4.x), v1 = bfb2f(a4.y), v2 = bfb2f(a4.z), v3 = bfb2f(a4.w);
                a0.x = fmaf(fv.x, v0, a0.x); a0.y = fmaf(fv.y, v0, a0.y);
                a1.x = fmaf(fv.x, v1, a1.x); a1.y = fmaf(fv.y, v1, a1.y);
                a2.x = fmaf(fv.x, v2, a2.x); a2.y = fmaf(fv.y, v2, a2.y);
                a3.x = fmaf(fv.x, v3, a3.x); a3.y = fmaf(fv.y, v3, a3.y);
            }
            uint4 w4 = *reinterpret_cast<const uint4*>(&cTwip[r*SFP + c0]);
            float2 w0 = upk(w4.x), w1 = upk(w4.y), w2 = upk(w4.z), w3 = upk(w4.w);
            float2 x0 = cmul2(a0, make_float2(w0.x*SC1K, -w0.y*SC1K));
            float2 x1 = cmul2(a1, make_float2(w1.x*SC1K, -w1.y*SC1K));
            float2 x2 = cmul2(a2, make_float2(w2.x*SC1K, -w2.y*SC1K));
            float2 x3 = cmul2(a3, make_float2(w3.x*SC1K, -w3.y*SC1K));
            *reinterpret_cast<float4*>(&b1[r*SB + c0    ]) = make_float4(x0.x, x0.y, x1.x, x1.y);
            *reinterpret_cast<float4*>(&b1[r*SB + c0 + 2]) = make_float4(x2.x, x2.y, x3.x, x3.y);
        }
        __syncthreads();

        // prefetch next u tile into registers (latency hidden under S2+S3)
        float4 pv;
        if (it < 15) {
            const size_t nbase = ((size_t)(it + 1) * 1024 + h) * 1024;
            pv = *reinterpret_cast<const float4*>(U + nbase + 4*t);
        }

        // S2: X2[i][m] = sum_c X1tw[i][c]*F[c][m] ; * kf[i][m] ; -> b2
        {
            float2 a0={0,0}, a1={0,0}, a2={0,0}, a3={0,0};
            #pragma unroll 16
            for (int c = 0; c < 32; ++c) {
                float2 xv = b1[r*SB + c];                       // row broadcast (b64)
                uint4 f4 = *reinterpret_cast<const uint4*>(&cFp[c*SFP + c0]);
                cmac2(a0, xv, upk(f4.x));
                cmac2(a1, xv, upk(f4.y));
                cmac2(a2, xv, upk(f4.z));
                cmac2(a3, xv, upk(f4.w));
            }
            uint4 k4 = *reinterpret_cast<const uint4*>(&cKfp[r*SFP + c0]);
            float2 y0 = cmul2(a0, upk(k4.x));
            float2 y1 = cmul2(a1, upk(k4.y));
            float2 y2 = cmul2(a2, upk(k4.z));
            float2 y3 = cmul2(a3, upk(k4.w));
            *reinterpret_cast<float4*>(&b2[r*SB + c0    ]) = make_float4(y0.x, y0.y, y1.x, y1.y);
            *reinterpret_cast<float4*>(&b2[r*SB + c0 + 2]) = make_float4(y2.x, y2.y, y3.x, y3.y);
        }
        __syncthreads();

        // S3: W[i][p] = sum_m Y[i][m]*conj(F[m][p]) ; * twinv ; -> b1
        {
            float2 a0={0,0}, a1={0,0}, a2={0,0}, a3={0,0};
            #pragma unroll 16
            for (int m = 0; m < 32; ++m) {
                float2 yv = b2[r*SB + m];                       // row broadcast (b64)
                uint4 g4 = *reinterpret_cast<const uint4*>(&cFp[m*SFP + c0]);
                cmacC(a0, yv, upk(g4.x));
                cmacC(a1, yv, upk(g4.y));
                cmacC(a2, yv, upk(g4.z));
                cmacC(a3, yv, upk(g4.w));
            }
            uint4 w4 = *reinterpret_cast<const uint4*>(&cTwip[r*SFP + c0]);
            float2 z0 = cmul2(a0, upk(w4.x));
            float2 z1 = cmul2(a1, upk(w4.y));
            float2 z2 = cmul2(a2, upk(w4.z));
            float2 z3 = cmul2(a3, upk(w4.w));
            *reinterpret_cast<float4*>(&b1[r*SB + c0    ]) = make_float4(z0.x, z0.y, z1.x, z1.y);
            *reinterpret_cast<float4*>(&b1[r*SB + c0 + 2]) = make_float4(z2.x, z2.y, z3.x, z3.y);
        }
        // write next tile's aAp (aAp unread until next S1; covered by S4's barrier)
        if (it < 15) {
            ushort4 av;
            av.x = f2bf(pv.x); av.y = f2bf(pv.y); av.z = f2bf(pv.z); av.w = f2bf(pv.w);
            *reinterpret_cast<ushort4*>(&aAp[r*SAP + c0]) = av;
        }
        __syncthreads();

        // S4: O[q][p] = Re( sum_i conj(F[q][i])*Z[i][p] ) ; coalesced store
        {
            float o0 = 0.f, o1 = 0.f, o2 = 0.f, o3 = 0.f;
            #pragma unroll 16
            for (int i = 0; i < 32; ++i) {
                float2 gv = upk(cFp[r*SFP + i]);                // row broadcast (b32)
                float4 p01 = *reinterpret_cast<const float4*>(&b1[i*SB + c0]);
                float4 p23 = *reinterpret_cast<const float4*>(&b1[i*SB + c0 + 2]);
                o0 = fmaf(gv.x, p01.x, o0); o0 = fmaf(gv.y, p01.y, o0);
                o1 = fmaf(gv.x, p01.z, o1); o1 = fmaf(gv.y, p01.w, o1);
                o2 = fmaf(gv.x, p23.x, o2); o2 = fmaf(gv.y, p23.y, o2);
                o3 = fmaf(gv.x, p23.z, o3); o3 = fmaf(gv.y, p23.w, o3);
            }
            *reinterpret_cast<float4*>(OUT + base + 4*t) = make_float4(o0, o1, o2, o3);
        }
        __syncthreads();
    }
}

extern "C" void kernel_launch(void* const* d_in, const int* in_sizes, int n_in,
                              void* d_out, int out_size, void* d_ws, size_t ws_size,
                              hipStream_t stream) {
    const float* U = (const float*)d_in[0];
    const float* K = (const float*)d_in[1];
    float* OUT = (float*)d_out;

    tkmon3<<<dim3(1024), dim3(256), 0, stream>>>(U, K, OUT);
}